// Round 2
// baseline (281.177 us; speedup 1.0000x reference)
//
#include <hip/hip_runtime.h>

// VelVector: per point n (N=500000), K=32 neighbors, D=3.
//   nd[k] = normalize(neighbors[n,k]-pos[n]); w[k] = MLP(nd[k]) (3->5->5->1);
//   out[n] = normalize(sum_k nd[k]*w[k])
//
// Mapping v2: 4 neighbors per lane (8 lanes per point, 8 points per wave).
// Each lane loads its 48 B of neighbor data as 3x float4 (16 B/lane, fully
// coalesced, issued up-front as 3 independent in-flight loads). This cuts
// VMEM load instructions 4x and wave count 4x vs the 1-neighbor/lane version,
// amortizing the wave-uniform weight loads / pos loads / butterfly / final
// normalize over 256 neighbors per wave instead of 64. Butterfly reduce is
// 3 steps over 8 lanes.
//
// NOTE: __builtin_nontemporal_load needs a clang native vector type, not
// HIP's float4 class -> use ext_vector_type(4).

#define K   32
#define LPP 8   // lanes per point
#define NPL 4   // neighbors per lane

typedef float f32x4 __attribute__((ext_vector_type(4)));

__global__ __launch_bounds__(256) void velvec_kernel(
    const float* __restrict__ pos,   // [N,3]
    const float* __restrict__ nbr,   // [N,K,3]
    const float* __restrict__ W1,    // [5,3]
    const float* __restrict__ b1,    // [5]
    const float* __restrict__ W2,    // [5,5]
    const float* __restrict__ b2,    // [5]
    const float* __restrict__ W3,    // [1,5]
    const float* __restrict__ b3,    // [1]
    float* __restrict__ out,         // [N,3]
    int N)
{
    const int tid   = blockIdx.x * blockDim.x + threadIdx.x;
    const int point = tid >> 3;                  // / LPP
    const int sub   = threadIdx.x & (LPP - 1);   // which 4-neighbor chunk
    if (point >= N) return;

    // ---- neighbor loads: 3 x float4 = 12 floats = 4 neighbors (48 B/lane) ----
    // nbr as f32x4: point owns K*3/4 = 24 vec4s; this lane takes 3 of them.
    const f32x4* nb4 = reinterpret_cast<const f32x4*>(nbr)
                     + (size_t)point * (K * 3 / 4) + sub * 3;
    const f32x4 f0 = __builtin_nontemporal_load(nb4 + 0);
    const f32x4 f1 = __builtin_nontemporal_load(nb4 + 1);
    const f32x4 f2 = __builtin_nontemporal_load(nb4 + 2);

    // ---- position (broadcast within 8-lane group: same addresses) ----
    const float px = pos[point * 3 + 0];
    const float py = pos[point * 3 + 1];
    const float pz = pos[point * 3 + 2];

    // ---- weights: uniform addresses -> compiler emits s_load (per-wave) ----
    float w1[5][3], bb1[5], w2[5][5], bb2[5], w3v[5];
#pragma unroll
    for (int h = 0; h < 5; ++h) {
        bb1[h] = b1[h];
        bb2[h] = b2[h];
        w3v[h] = W3[h];
#pragma unroll
        for (int d = 0; d < 3; ++d) w1[h][d] = W1[h * 3 + d];
#pragma unroll
        for (int g = 0; g < 5; ++g) w2[h][g] = W2[h * 5 + g];
    }
    const float bb3 = b3[0];

    // unpack 12 floats -> 4 neighbor xyz triples (all indices static after unroll)
    const float nx[NPL] = { f0.x, f0.w, f1.z, f2.y };
    const float ny[NPL] = { f0.y, f1.x, f1.w, f2.z };
    const float nz[NPL] = { f0.z, f1.y, f2.x, f2.w };

    float vx = 0.0f, vy = 0.0f, vz = 0.0f;
#pragma unroll
    for (int j = 0; j < NPL; ++j) {
        // diff + normalize: v / max(||v||, 1e-12)
        float dx = nx[j] - px;
        float dy = ny[j] - py;
        float dz = nz[j] - pz;
        float n2 = fmaf(dx, dx, fmaf(dy, dy, dz * dz));
        float inv = (n2 > 1e-24f) ? __builtin_amdgcn_rsqf(n2) : 1e12f;
        dx *= inv; dy *= inv; dz *= inv;

        // tiny MLP: 3 -> 5 (relu) -> 5 (relu) -> 1
        float h1[5];
#pragma unroll
        for (int h = 0; h < 5; ++h) {
            float a = bb1[h];
            a = fmaf(w1[h][0], dx, a);
            a = fmaf(w1[h][1], dy, a);
            a = fmaf(w1[h][2], dz, a);
            h1[h] = fmaxf(a, 0.0f);
        }
        float h2[5];
#pragma unroll
        for (int g = 0; g < 5; ++g) {
            float a = bb2[g];
#pragma unroll
            for (int h = 0; h < 5; ++h) a = fmaf(w2[g][h], h1[h], a);
            h2[g] = fmaxf(a, 0.0f);
        }
        float w = bb3;
#pragma unroll
        for (int h = 0; h < 5; ++h) w = fmaf(w3v[h], h2[h], w);

        // accumulate weighted direction (4 neighbors locally in-register)
        vx = fmaf(dx, w, vx);
        vy = fmaf(dy, w, vy);
        vz = fmaf(dz, w, vz);
    }

    // ---- butterfly reduce over the 8 lanes of this point (3 steps) ----
#pragma unroll
    for (int m = LPP / 2; m > 0; m >>= 1) {
        vx += __shfl_xor(vx, m, LPP);
        vy += __shfl_xor(vy, m, LPP);
        vz += __shfl_xor(vz, m, LPP);
    }

    // ---- final normalize + store (lanes 0..2 of each group write x,y,z) ----
    float vn2  = fmaf(vx, vx, fmaf(vy, vy, vz * vz));
    float vinv = (vn2 > 1e-24f) ? __builtin_amdgcn_rsqf(vn2) : 1e12f;
    if (sub < 3) {
        float c = (sub == 0) ? vx : (sub == 1) ? vy : vz;
        out[point * 3 + sub] = c * vinv;
    }
}

extern "C" void kernel_launch(void* const* d_in, const int* in_sizes, int n_in,
                              void* d_out, int out_size, void* d_ws, size_t ws_size,
                              hipStream_t stream) {
    const float* pos = (const float*)d_in[0];
    const float* nbr = (const float*)d_in[1];
    const float* W1  = (const float*)d_in[2];
    const float* b1  = (const float*)d_in[3];
    const float* W2  = (const float*)d_in[4];
    const float* b2  = (const float*)d_in[5];
    const float* W3  = (const float*)d_in[6];
    const float* b3  = (const float*)d_in[7];
    float* out = (float*)d_out;

    const int N = in_sizes[0] / 3;              // 500000
    const int threads = 256;                    // 32 points per block
    const long long total = (long long)N * LPP; // one lane per (point, 4-neighbor chunk)
    const int blocks = (int)((total + threads - 1) / threads);

    velvec_kernel<<<blocks, threads, 0, stream>>>(pos, nbr, W1, b1, W2, b2, W3, b3,
                                                  out, N);
}